// Round 17
// baseline (189.500 us; speedup 1.0000x reference)
//
#include <hip/hip_runtime.h>

// CGConv x2 + masked readout. N=50000, E=800000, C=64.
// R17: (a) glean guard-free pads (dummy Ps row [0,-448] -> msg==0), sentinel
// nend (1 cmp), 16-deep load banks; (b) parallel Hillis-Steele scans replace
// the serial t==0 prefix loops in scan196/bin/group (were ~10-20us combined);
// (c) k_final folded into k_post2 (done-counter).
//
// ws: deg(1024) scal(64) cbase(788@1088) gcursor(784@2048) start(200004@4096)
//     ebuf1(3.2M@204800) esrc(3.2M) h1b(6.4M) Pd(12.8M) Ps(6.4M+128) agg(6.4M) wt(64K)

#define NN 50000
#define EE 800000
#define NB1 196           // coarse buckets (256 nodes each)
#define BSZ 256
#define CHK 4096
#define GCAP 5120
#define NTILE 782
#define NWAVES 8192
#define EPW 98
#define PADOFF 6406144    // byte offset of dummy Ps row (row 50048)

typedef short bf16x8 __attribute__((ext_vector_type(8)));
typedef float f32x4 __attribute__((ext_vector_type(4)));
typedef unsigned int uint4v __attribute__((ext_vector_type(4)));
typedef unsigned short u16x4 __attribute__((ext_vector_type(4)));
typedef int int4v __attribute__((ext_vector_type(4)));

#define LN2F 0.6931471805599453f
#define L2EF 1.4426950408889634f

#if __has_builtin(__builtin_amdgcn_exp2f)
#define EXP2(x) __builtin_amdgcn_exp2f(x)
#else
#define EXP2(x) __expf(LN2F * (x))
#endif
#if __has_builtin(__builtin_amdgcn_logf)
#define LOG2(x) __builtin_amdgcn_logf(x)
#else
#define LOG2(x) (L2EF * __logf(x))
#endif
#if __has_builtin(__builtin_amdgcn_rcpf)
#define RCPF(x) __builtin_amdgcn_rcpf(x)
#else
#define RCPF(x) (1.0f / (x))
#endif

__device__ __forceinline__ unsigned short f2b(float f) {
    unsigned int u = __builtin_bit_cast(unsigned int, f);
    return (unsigned short)((u + 0x7fffu + ((u >> 16) & 1u)) >> 16);
}
__device__ __forceinline__ float b2f(unsigned short b) {
    unsigned int u = ((unsigned int)b) << 16;
    return __builtin_bit_cast(float, u);
}
__device__ __forceinline__ float lo16f(unsigned int v) {
    return __builtin_bit_cast(float, v << 16);
}
__device__ __forceinline__ float hi16f(unsigned int v) {
    return __builtin_bit_cast(float, v & 0xFFFF0000u);
}

__device__ __forceinline__ unsigned char f2fp8(float f) {
#if __has_builtin(__builtin_amdgcn_cvt_pk_fp8_f32)
    return (unsigned char)(__builtin_amdgcn_cvt_pk_fp8_f32(f, f, 0, false) & 0xff);
#else
    float a = fabsf(f); if (a > 448.f) a = 448.f;
    int e2; float m = frexpf(a, &e2);
    int E = e2 + 6;
    unsigned char r;
    if (a < 0.001953125f) {
        r = (unsigned char)(a * 512.f + 0.5f);
    } else {
        int mant = (int)(m * 16.f + 0.5f) - 8;
        if (mant == 8) { mant = 0; ++E; }
        if (E > 15) { E = 15; mant = 7; }
        r = (unsigned char)((E << 3) | mant);
    }
    return r | (f < 0.f ? 0x80 : 0);
#endif
}
__device__ __forceinline__ float fp8lo(unsigned int v) {
#if __has_builtin(__builtin_amdgcn_cvt_f32_fp8)
    return __builtin_amdgcn_cvt_f32_fp8(v, 0);
#else
    unsigned b = v & 0xff;
    unsigned s = b >> 7, e = (b >> 3) & 15, mn = b & 7;
    float mag = e ? __builtin_ldexpf(1.f + mn * 0.125f, (int)e - 7)
                  : __builtin_ldexpf((float)mn, -9);
    return s ? -mag : mag;
#endif
}
__device__ __forceinline__ float fp8hi(unsigned int v) {
#if __has_builtin(__builtin_amdgcn_cvt_f32_fp8)
    return __builtin_amdgcn_cvt_f32_fp8(v, 1);
#else
    return fp8lo(v >> 8);
#endif
}

// per-edge message / ln2, pre-scaled: nF = -log2e*F, Sp = log2e*S
__device__ __forceinline__ float msg2(float nF, float Sp) {
    return RCPF(1.f + EXP2(nF)) * LOG2(1.f + EXP2(Sp));
}

// 196-bucket LDS histogram + weight prep. 98 blocks x 1024.
__global__ __launch_bounds__(1024) void k_hist(const int* __restrict__ ei, int* __restrict__ deg,
                                               const float* __restrict__ Wf1, const float* __restrict__ Ws1,
                                               const float* __restrict__ Wf2, const float* __restrict__ Ws2,
                                               unsigned short* __restrict__ wt) {
    __shared__ int hist[NB1];
    int t = threadIdx.x;
    if (t < NB1) hist[t] = 0;
    int gi = blockIdx.x * 1024 + t;
    if (gi < 32768) {
        int layer = gi >> 14;
        int j = gi & 16383;
        int n = j >> 6, k = j & 63;
        const float* Wf = layer ? Wf2 : Wf1;
        const float* Ws = layer ? Ws2 : Ws1;
        float v;
        if (n < 64)       v = Wf[k * 64 + n];
        else if (n < 128) v = Ws[k * 64 + (n - 64)];
        else if (n < 192) v = Wf[(64 + k) * 64 + (n - 128)];
        else              v = Ws[(64 + k) * 64 + (n - 192)];
        int byte = ((n * 128 + k * 2) ^ ((n & 7) << 4)) + layer * 32768;
        *(unsigned short*)((char*)wt + byte) = f2b(v);
    }
    __syncthreads();
    for (int e = gi; e < EE; e += 98 * 1024)
        atomicAdd(&hist[ei[EE + e] >> 8], 1);
    __syncthreads();
    if (t < NB1 && hist[t]) atomicAdd(&deg[t], hist[t]);
}

// parallel scan of bucket counts; start[NN] sentinel; dummy Ps row init.
__global__ __launch_bounds__(256) void k_scan196(const int* __restrict__ deg, int* __restrict__ cbase,
                                                 int* __restrict__ gcursor, int* __restrict__ start,
                                                 unsigned char* __restrict__ Ps) {
    __shared__ int sc[256];
    int t = threadIdx.x;
    int v = (t < NB1) ? deg[t] : 0;
    sc[t] = v; __syncthreads();
    for (int off = 1; off < 256; off <<= 1) {
        int y = (t >= off) ? sc[t - off] : 0; __syncthreads();
        sc[t] += y; __syncthreads();
    }
    if (t < NB1) {
        int ex = sc[t] - v;
        cbase[t] = ex;
        gcursor[t] = ex;
    }
    if (t == NB1 - 1) cbase[NB1] = sc[t];
    if (t == 0) start[NN] = EE;
    if (t < 64) ((unsigned short*)(Ps + PADOFF))[t] = 0xFF00;  // [F8=0|S8=-448]
}

// chunk -> LDS sort by bucket -> coalesced run writeout. 196 blocks x 1024.
__global__ __launch_bounds__(1024) void k_bin(const int* __restrict__ ei, int* __restrict__ gcursor,
                                              unsigned int* __restrict__ ebuf1) {
    __shared__ int hist[NB1];
    __shared__ int lpre[NB1 + 1];
    __shared__ int gbase[NB1];
    __shared__ int sc[256];
    __shared__ unsigned int staged[CHK];
    int t = threadIdx.x;
    if (t < NB1) hist[t] = 0;
    __syncthreads();
    int e0 = blockIdx.x * CHK;
    unsigned int pk[4]; int rk[4], bk[4];
    #pragma unroll
    for (int i = 0; i < 4; ++i) {
        int e = e0 + t + 1024 * i;
        if (e < EE) {
            int src = ei[e], dst = ei[EE + e];
            bk[i] = dst >> 8;
            pk[i] = ((unsigned)(dst & 255) << 17) | (unsigned)src;
            rk[i] = atomicAdd(&hist[bk[i]], 1);
        } else bk[i] = -1;
    }
    __syncthreads();
    {   // parallel exclusive scan of hist -> lpre
        int hv = (t < 256) ? ((t < NB1) ? hist[t] : 0) : 0;
        if (t < 256) sc[t] = hv;
        __syncthreads();
        for (int off = 1; off < 256; off <<= 1) {
            int y = (t < 256 && t >= off) ? sc[t - off] : 0; __syncthreads();
            if (t < 256) sc[t] += y;
            __syncthreads();
        }
        if (t < NB1) lpre[t] = sc[t] - hv;
        if (t == NB1 - 1) lpre[NB1] = sc[t];
        __syncthreads();
    }
    if (t < NB1 && hist[t]) gbase[t] = atomicAdd(&gcursor[t], hist[t]);
    #pragma unroll
    for (int i = 0; i < 4; ++i)
        if (bk[i] >= 0) staged[lpre[bk[i]] + rk[i]] = pk[i];
    __syncthreads();
    int total = lpre[NB1];
    for (int k = t; k < total; k += 1024) {
        int lo = 0, hi = NB1 - 1;
        while (lo < hi) { int mid = (lo + hi + 1) >> 1; if (lpre[mid] <= k) lo = mid; else hi = mid - 1; }
        ebuf1[gbase[lo] + (k - lpre[lo])] = staged[k];
    }
}

// exact per-node grouping within a bucket; coalesced esrc (byte offsets
// src*128) + per-node start.
__global__ __launch_bounds__(1024) void k_group(const unsigned int* __restrict__ ebuf1,
                                                const int* __restrict__ cbase,
                                                int* __restrict__ esrc, int* __restrict__ start) {
    __shared__ int hist[BSZ];
    __shared__ int lpre[BSZ];
    __shared__ int sc[BSZ];
    __shared__ int staged[GCAP];
    int t = threadIdx.x;
    int b = blockIdx.x;
    if (t < BSZ) hist[t] = 0;
    __syncthreads();
    int e0 = cbase[b], e1 = cbase[b + 1];
    int cnt = e1 - e0;
    if (cnt > GCAP) cnt = GCAP;
    int src[5], rk[5], dl[5]; int m = 0;
    for (int k = t; k < cnt; k += 1024) {
        unsigned int p = ebuf1[e0 + k];
        int d = (int)(p >> 17);
        src[m] = (int)(p & 0x1FFFFu);
        dl[m] = d;
        rk[m] = atomicAdd(&hist[d], 1);
        if (++m == 5) break;
    }
    __syncthreads();
    {   // parallel exclusive scan hist -> lpre
        int hv = (t < BSZ) ? hist[t] : 0;
        if (t < BSZ) sc[t] = hv;
        __syncthreads();
        for (int off = 1; off < BSZ; off <<= 1) {
            int y = (t < BSZ && t >= off) ? sc[t - off] : 0; __syncthreads();
            if (t < BSZ) sc[t] += y;
            __syncthreads();
        }
        if (t < BSZ) lpre[t] = sc[t] - hv;
        __syncthreads();
    }
    for (int i = 0; i < m; ++i)
        staged[lpre[dl[i]] + rk[i]] = src[i];
    __syncthreads();
    for (int k = t; k < cnt; k += 1024)
        esrc[e0 + k] = staged[k] * 128;     // byte offset into Ps
    int node = b * BSZ + t;
    if (t < BSZ && node < NN)
        start[node] = e0 + lpre[t];
}

// P = H @ Wcat (R16). MODE 0: layer1 (x). MODE 1: layer2 fused residual.
// Epilogue: LDS-staged Pd/Ps tiles (reusing w_s), coalesced uint4 dump.
template <int MODE>
__global__ __launch_bounds__(256) void k_proj(const float* __restrict__ x,
                                              const unsigned short* __restrict__ agg,
                                              unsigned short* __restrict__ h1b,
                                              const unsigned short* __restrict__ wt,
                                              const float* __restrict__ bfv, const float* __restrict__ bsv,
                                              unsigned short* __restrict__ Pd, unsigned char* __restrict__ Ps) {
    __shared__ unsigned short w_s[256 * 64];
    __shared__ unsigned short a_s[64 * 64];
    const int t = threadIdx.x;
    {
        const uint4v* src = (const uint4v*)wt;
        uint4v* dp = (uint4v*)w_s;
        #pragma unroll
        for (int i = 0; i < 8; ++i) dp[t + 256 * i] = src[t + 256 * i];
    }
    const int lane = t & 63, wid = t >> 6;
    const int cbase = lane & 15, q = lane >> 4;
    const int tile = blockIdx.x;

    #pragma unroll
    for (int i = 0; i < 2; ++i) {
        int ch = t + 256 * i;
        int r = ch >> 3, c8 = ch & 7;
        int node = tile * 64 + r;
        u16x4 lo = {0, 0, 0, 0}, hi = {0, 0, 0, 0};
        if (node < NN) {
            const float* xp = x + node * 64 + c8 * 8;
            f32x4 v0 = *(const f32x4*)xp;
            f32x4 v1 = *(const f32x4*)(xp + 4);
            if (MODE == 1) {
                const unsigned short* ap = agg + node * 64 + c8 * 8;
                u16x4 a0 = *(const u16x4*)ap;
                u16x4 a1 = *(const u16x4*)(ap + 4);
                #pragma unroll
                for (int j = 0; j < 4; ++j) {
                    v0[j] += LN2F * b2f(a0[j]);
                    v1[j] += LN2F * b2f(a1[j]);
                }
            }
            lo[0] = f2b(v0[0]); lo[1] = f2b(v0[1]); lo[2] = f2b(v0[2]); lo[3] = f2b(v0[3]);
            hi[0] = f2b(v1[0]); hi[1] = f2b(v1[1]); hi[2] = f2b(v1[2]); hi[3] = f2b(v1[3]);
            if (MODE == 1) {
                unsigned short* hp = h1b + node * 64 + c8 * 8;
                *(u16x4*)hp = lo;
                *(u16x4*)(hp + 4) = hi;
            }
        }
        int byte = (r * 128 + c8 * 16) ^ ((r & 7) << 4);
        *(u16x4*)((char*)a_s + byte) = lo;
        *(u16x4*)((char*)a_s + byte + 8) = hi;
    }
    __syncthreads();

    f32x4 acc[4][4];
    #pragma unroll
    for (int m = 0; m < 4; ++m)
        #pragma unroll
        for (int n = 0; n < 4; ++n) acc[m][n] = (f32x4){0.f, 0.f, 0.f, 0.f};

    #pragma unroll
    for (int ks = 0; ks < 2; ++ks) {
        bf16x8 a[4];
        #pragma unroll
        for (int m = 0; m < 4; ++m) {
            int mr = m * 16 + cbase;
            a[m] = *(const bf16x8*)((const char*)a_s + mr * 128 + ((ks * 64 + q * 16) ^ ((mr & 7) << 4)));
        }
        #pragma unroll
        for (int n = 0; n < 4; ++n) {
            int bn = wid * 64 + n * 16 + cbase;
            bf16x8 b = *(const bf16x8*)((const char*)w_s + bn * 128 + ((ks * 64 + q * 16) ^ ((bn & 7) << 4)));
            #pragma unroll
            for (int m = 0; m < 4; ++m)
                acc[m][n] = __builtin_amdgcn_mfma_f32_16x16x32_bf16(a[m], b, acc[m][n], 0, 0, 0);
        }
    }

    __syncthreads();
    unsigned short* pdo = w_s;                              // 64x128 u16 (16KB)
    unsigned char*  pso = (unsigned char*)(w_s + 8192);     // 64x128 u8 (8KB)

    #pragma unroll
    for (int n = 0; n < 4; ++n) {
        int col = wid * 64 + n * 16 + cbase;
        if (col < 128) {
            int oidx = (col < 64) ? 2 * col : 2 * (col - 64) + 1;
            float scale = (col < 64) ? -L2EF : L2EF;
            #pragma unroll
            for (int m = 0; m < 4; ++m) {
                int row = m * 16 + q * 4;
                #pragma unroll
                for (int r = 0; r < 4; ++r)
                    pdo[(row + r) * 128 + oidx] = f2b(acc[m][n][r] * scale);
            }
        } else {
            float bias, scale; int boff;
            if (col < 192) { scale = -L2EF; bias = bfv[col - 128]; boff = 2 * (col - 128); }
            else           { scale =  L2EF; bias = bsv[col - 192]; boff = 2 * (col - 192) + 1; }
            #pragma unroll
            for (int m = 0; m < 4; ++m) {
                int row = m * 16 + q * 4;
                #pragma unroll
                for (int r = 0; r < 4; ++r)
                    pso[(row + r) * 128 + boff] = f2fp8((acc[m][n][r] + bias) * scale);
            }
        }
    }
    __syncthreads();
    {
        uint4v* pdg = (uint4v*)(Pd + tile * 64 * 128);
        const uint4v* pdl = (const uint4v*)pdo;
        #pragma unroll
        for (int i = 0; i < 4; ++i) pdg[t + 256 * i] = pdl[t + 256 * i];
        uint4v* psg = (uint4v*)(Ps + tile * 64 * 128);
        const uint4v* psl = (const uint4v*)pso;
        #pragma unroll
        for (int i = 0; i < 2; ++i) psg[t + 256 * i] = psl[t + 256 * i];
    }
}

// Gather: guard-free (pads -> dummy row, msg==0), sentinel nend, 16-deep banks.
__global__ __launch_bounds__(256) void k_glean(const unsigned int* __restrict__ Pd,
                                               const unsigned char* __restrict__ Ps,
                                               const int* __restrict__ esrc, const int* __restrict__ start,
                                               unsigned short* __restrict__ agg) {
    __shared__ int idx_s[4][240];
    __shared__ int end_s[4][32];
    __shared__ unsigned int pd_s[4][1024];
    const int lane = threadIdx.x & 63;
    const int wid = threadIdx.x >> 6;
    const int w = blockIdx.x * 4 + wid;

    int t0 = w * EPW, t1 = t0 + EPW;
    int lo = 0, hi = NN;
    while (lo < hi) { int mid = (lo + hi) >> 1; if (start[mid] < t0) lo = mid + 1; else hi = mid; }
    const int n0 = lo;
    hi = NN;
    while (lo < hi) { int mid = (lo + hi) >> 1; if (start[mid] < t1) lo = mid + 1; else hi = mid; }
    const int n1 = lo;
    const int nn = n1 - n0;
    const int nn16 = (nn < 16) ? nn : 16;

    const int e0 = __builtin_amdgcn_readfirstlane(start[n0]);
    const int cnt = __builtin_amdgcn_readfirstlane(start[n1]) - e0;
    int* idxp = idx_s[wid];
    for (int k = lane; k < cnt + 32; k += 64)
        idxp[k] = (k < cnt) ? esrc[e0 + k] : PADOFF;
    int* endp = end_s[wid];
    if (lane < 32)
        endp[lane] = (lane < nn && lane < 31) ? (start[n0 + 1 + lane] - e0) : 0x7fffffff;
    unsigned int* pdp = pd_s[wid];
    for (int i = 0; i < nn16; ++i)
        pdp[i * 64 + lane] = Pd[(n0 + i) * 64 + lane];

    const char* Psc = (const char*)Ps;
    const int lane2 = lane * 2;

    int n = n0;
    int nend = 0x7fffffff;
    float acc = 0.f, nfd = 0.f, sd = 0.f;
    if (nn > 0) {
        unsigned int pv = pdp[lane];
        nfd = lo16f(pv); sd = hi16f(pv);
        nend = endp[0];
    }

#define FLUSH() do {                                                          \
    agg[n * 64 + lane] = f2b(acc);                                            \
    ++n; acc = 0.f;                                                           \
    int ii_ = n - n0;                                                         \
    unsigned int pv_;                                                         \
    if (ii_ < 16) pv_ = pdp[ii_ * 64 + lane];                                 \
    else pv_ = Pd[((n < NN) ? n : NN - 1) * 64 + lane];                       \
    nfd = lo16f(pv_); sd = hi16f(pv_);                                        \
    nend = (ii_ < 31) ? endp[ii_]                                             \
                      : ((n < n1) ? (__builtin_amdgcn_readfirstlane(start[n + 1]) - e0) \
                                  : 0x7fffffff);                              \
} while (0)

#define LOADB(vv, kb_) do {                                                   \
    _Pragma("unroll")                                                         \
    for (int j_ = 0; j_ < 4; ++j_) {                                          \
        int4v jj_ = *(const int4v*)(idxp + (kb_) + j_ * 4);                   \
        vv[j_ * 4 + 0] = *(const unsigned short*)(Psc + jj_[0] + lane2);      \
        vv[j_ * 4 + 1] = *(const unsigned short*)(Psc + jj_[1] + lane2);      \
        vv[j_ * 4 + 2] = *(const unsigned short*)(Psc + jj_[2] + lane2);      \
        vv[j_ * 4 + 3] = *(const unsigned short*)(Psc + jj_[3] + lane2);      \
    }                                                                         \
} while (0)

#define COMP(vv, kb_) do {                                                    \
    _Pragma("unroll")                                                         \
    for (int i_ = 0; i_ < 16; ++i_) {                                         \
        int k_ = (kb_) + i_;                                                  \
        while (k_ == nend) FLUSH();                                           \
        acc += msg2(nfd + fp8lo(vv[i_]), sd + fp8hi(vv[i_]));                 \
    }                                                                         \
} while (0)

    if (cnt > 0) {
        unsigned int vA[16], vB[16];
        LOADB(vA, 0);
        int kb = 0;
        while (true) {
            LOADB(vB, kb + 16);
            COMP(vA, kb);
            kb += 16; if (kb >= cnt) break;
            LOADB(vA, kb + 16);
            COMP(vB, kb);
            kb += 16; if (kb >= cnt) break;
        }
    }
    while (n < n1) FLUSH();
#undef FLUSH
#undef LOADB
#undef COMP
}

// readout + fused final (done-counter in scal[2]).
__global__ __launch_bounds__(256) void k_post2(const unsigned short* __restrict__ h1b,
                                               const unsigned short* __restrict__ agg,
                                               const float* __restrict__ surf, const float* __restrict__ Wlin,
                                               const float* __restrict__ blin,
                                               float* __restrict__ scal, float* __restrict__ out) {
    const int lane = threadIdx.x & 63, wid = threadIdx.x >> 6;
    float wl = Wlin[lane];
    float so = 0.f, ss = 0.f;
    for (int n = blockIdx.x * 4 + wid; n < NN; n += gridDim.x * 4) {
        int i = n * 64 + lane;
        float h2 = b2f(h1b[i]) + LN2F * b2f(agg[i]);
        float v = h2 * wl;
        #pragma unroll
        for (int off = 32; off; off >>= 1) v += __shfl_xor(v, off);
        if (lane == 0) { so += v * surf[n]; ss += surf[n]; }
    }
    __shared__ float ps[8];
    if (lane == 0) { ps[wid] = so; ps[4 + wid] = ss; }
    __syncthreads();
    if (threadIdx.x == 0) {
        atomicAdd(scal + 0, ps[0] + ps[1] + ps[2] + ps[3]);
        atomicAdd(scal + 1, ps[4] + ps[5] + ps[6] + ps[7]);
        __threadfence();
        unsigned done = atomicAdd((unsigned int*)(scal + 2), 1u);
        if (done == gridDim.x - 1) {
            float num = atomicAdd(scal + 0, 0.f);   // coherent reads
            float den = atomicAdd(scal + 1, 0.f);
            out[0] = (num + (float)NN * blin[0]) / den;
        }
    }
}

extern "C" void kernel_launch(void* const* d_in, const int* in_sizes, int n_in,
                              void* d_out, int out_size, void* d_ws, size_t ws_size,
                              hipStream_t stream) {
    const float* x    = (const float*)d_in[0];
    const int*   ei   = (const int*)d_in[1];
    const float* surf = (const float*)d_in[2];
    const float* Wf1  = (const float*)d_in[3];
    const float* bf1  = (const float*)d_in[4];
    const float* Ws1  = (const float*)d_in[5];
    const float* bs1  = (const float*)d_in[6];
    const float* Wf2  = (const float*)d_in[7];
    const float* bf2  = (const float*)d_in[8];
    const float* Ws2  = (const float*)d_in[9];
    const float* bs2  = (const float*)d_in[10];
    const float* Wlin = (const float*)d_in[11];
    const float* blin = (const float*)d_in[12];

    unsigned char* ws = (unsigned char*)d_ws;
    int* deg      = (int*)(ws);                              // 784 (pad 1024)
    float* scal   = (float*)(ws + 1024);                     // 64 (scal[2]=done)
    int* cbase    = (int*)(ws + 1088);                       // 788 (pad to 2048)
    int* gcursor  = (int*)(ws + 2048);                       // 784
    int* start    = (int*)(ws + 4096);                       // 200,004
    unsigned int* ebuf1 = (unsigned int*)(ws + 204800);      // 3,200,000
    int* esrc     = (int*)(ws + 3404800);                    // 3,200,000
    unsigned short* h1b = (unsigned short*)(ws + 6604800);   // 6,406,144
    unsigned short* Pd  = (unsigned short*)(ws + 13010944);  // 12,812,288
    unsigned char*  Ps  = (unsigned char*)(ws + 25823232);   // 6,406,144 + 128 (dummy row)
    unsigned short* agg = (unsigned short*)(ws + 32229504);  // 6,406,144
    unsigned short* wt  = (unsigned short*)(ws + 38635648);  // 65,536

    hipMemsetAsync(d_ws, 0, 1088, stream);  // deg + scal (incl done-counter)

    k_hist<<<98, 1024, 0, stream>>>(ei, deg, Wf1, Ws1, Wf2, Ws2, wt);
    k_scan196<<<1, 256, 0, stream>>>(deg, cbase, gcursor, start, Ps);
    k_bin<<<196, 1024, 0, stream>>>(ei, gcursor, ebuf1);
    k_group<<<196, 1024, 0, stream>>>(ebuf1, cbase, esrc, start);

    k_proj<0><<<NTILE, 256, 0, stream>>>(x, agg, h1b, wt, bf1, bs1, Pd, Ps);
    k_glean<<<2048, 256, 0, stream>>>((const unsigned int*)Pd, Ps, esrc, start, agg);
    k_proj<1><<<NTILE, 256, 0, stream>>>(x, agg, h1b, wt + 16384, bf2, bs2, Pd, Ps);
    k_glean<<<2048, 256, 0, stream>>>((const unsigned int*)Pd, Ps, esrc, start, agg);
    k_post2<<<512, 256, 0, stream>>>(h1b, agg, surf, Wlin, blin, scal, (float*)d_out);
}

// Round 18
// 182.230 us; speedup vs baseline: 1.0399x; 1.0399x over previous
//
#include <hip/hip_runtime.h>

// CGConv x2 + masked readout. N=50000, E=800000, C=64.
// R18: R17 prep chain (parallel scans, fused final) + glean back to 8-deep
// load banks (R17's 16-deep processed up to 31 dummy pad edges/wave = ~16%
// extra trans math, +8 VGPR). Keeps guard-free pads (dummy Ps row -> msg==0)
// and sentinel nend from R17 -- those remove per-edge cmp/cndmask at no cost.
//
// ws: deg(1024) scal(64) cbase(788@1088) gcursor(784@2048) start(200004@4096)
//     ebuf1(3.2M@204800) esrc(3.2M) h1b(6.4M) Pd(12.8M) Ps(6.4M+128) agg(6.4M) wt(64K)

#define NN 50000
#define EE 800000
#define NB1 196           // coarse buckets (256 nodes each)
#define BSZ 256
#define CHK 4096
#define GCAP 5120
#define NTILE 782
#define NWAVES 8192
#define EPW 98
#define PADOFF 6406144    // byte offset of dummy Ps row (row 50048)

typedef short bf16x8 __attribute__((ext_vector_type(8)));
typedef float f32x4 __attribute__((ext_vector_type(4)));
typedef unsigned int uint4v __attribute__((ext_vector_type(4)));
typedef unsigned short u16x4 __attribute__((ext_vector_type(4)));
typedef int int4v __attribute__((ext_vector_type(4)));

#define LN2F 0.6931471805599453f
#define L2EF 1.4426950408889634f

#if __has_builtin(__builtin_amdgcn_exp2f)
#define EXP2(x) __builtin_amdgcn_exp2f(x)
#else
#define EXP2(x) __expf(LN2F * (x))
#endif
#if __has_builtin(__builtin_amdgcn_logf)
#define LOG2(x) __builtin_amdgcn_logf(x)
#else
#define LOG2(x) (L2EF * __logf(x))
#endif
#if __has_builtin(__builtin_amdgcn_rcpf)
#define RCPF(x) __builtin_amdgcn_rcpf(x)
#else
#define RCPF(x) (1.0f / (x))
#endif

__device__ __forceinline__ unsigned short f2b(float f) {
    unsigned int u = __builtin_bit_cast(unsigned int, f);
    return (unsigned short)((u + 0x7fffu + ((u >> 16) & 1u)) >> 16);
}
__device__ __forceinline__ float b2f(unsigned short b) {
    unsigned int u = ((unsigned int)b) << 16;
    return __builtin_bit_cast(float, u);
}
__device__ __forceinline__ float lo16f(unsigned int v) {
    return __builtin_bit_cast(float, v << 16);
}
__device__ __forceinline__ float hi16f(unsigned int v) {
    return __builtin_bit_cast(float, v & 0xFFFF0000u);
}

__device__ __forceinline__ unsigned char f2fp8(float f) {
#if __has_builtin(__builtin_amdgcn_cvt_pk_fp8_f32)
    return (unsigned char)(__builtin_amdgcn_cvt_pk_fp8_f32(f, f, 0, false) & 0xff);
#else
    float a = fabsf(f); if (a > 448.f) a = 448.f;
    int e2; float m = frexpf(a, &e2);
    int E = e2 + 6;
    unsigned char r;
    if (a < 0.001953125f) {
        r = (unsigned char)(a * 512.f + 0.5f);
    } else {
        int mant = (int)(m * 16.f + 0.5f) - 8;
        if (mant == 8) { mant = 0; ++E; }
        if (E > 15) { E = 15; mant = 7; }
        r = (unsigned char)((E << 3) | mant);
    }
    return r | (f < 0.f ? 0x80 : 0);
#endif
}
__device__ __forceinline__ float fp8lo(unsigned int v) {
#if __has_builtin(__builtin_amdgcn_cvt_f32_fp8)
    return __builtin_amdgcn_cvt_f32_fp8(v, 0);
#else
    unsigned b = v & 0xff;
    unsigned s = b >> 7, e = (b >> 3) & 15, mn = b & 7;
    float mag = e ? __builtin_ldexpf(1.f + mn * 0.125f, (int)e - 7)
                  : __builtin_ldexpf((float)mn, -9);
    return s ? -mag : mag;
#endif
}
__device__ __forceinline__ float fp8hi(unsigned int v) {
#if __has_builtin(__builtin_amdgcn_cvt_f32_fp8)
    return __builtin_amdgcn_cvt_f32_fp8(v, 1);
#else
    return fp8lo(v >> 8);
#endif
}

// per-edge message / ln2, pre-scaled: nF = -log2e*F, Sp = log2e*S
__device__ __forceinline__ float msg2(float nF, float Sp) {
    return RCPF(1.f + EXP2(nF)) * LOG2(1.f + EXP2(Sp));
}

// 196-bucket LDS histogram + weight prep. 98 blocks x 1024.
__global__ __launch_bounds__(1024) void k_hist(const int* __restrict__ ei, int* __restrict__ deg,
                                               const float* __restrict__ Wf1, const float* __restrict__ Ws1,
                                               const float* __restrict__ Wf2, const float* __restrict__ Ws2,
                                               unsigned short* __restrict__ wt) {
    __shared__ int hist[NB1];
    int t = threadIdx.x;
    if (t < NB1) hist[t] = 0;
    int gi = blockIdx.x * 1024 + t;
    if (gi < 32768) {
        int layer = gi >> 14;
        int j = gi & 16383;
        int n = j >> 6, k = j & 63;
        const float* Wf = layer ? Wf2 : Wf1;
        const float* Ws = layer ? Ws2 : Ws1;
        float v;
        if (n < 64)       v = Wf[k * 64 + n];
        else if (n < 128) v = Ws[k * 64 + (n - 64)];
        else if (n < 192) v = Wf[(64 + k) * 64 + (n - 128)];
        else              v = Ws[(64 + k) * 64 + (n - 192)];
        int byte = ((n * 128 + k * 2) ^ ((n & 7) << 4)) + layer * 32768;
        *(unsigned short*)((char*)wt + byte) = f2b(v);
    }
    __syncthreads();
    for (int e = gi; e < EE; e += 98 * 1024)
        atomicAdd(&hist[ei[EE + e] >> 8], 1);
    __syncthreads();
    if (t < NB1 && hist[t]) atomicAdd(&deg[t], hist[t]);
}

// parallel scan of bucket counts; start[NN] sentinel; dummy Ps row init.
__global__ __launch_bounds__(256) void k_scan196(const int* __restrict__ deg, int* __restrict__ cbase,
                                                 int* __restrict__ gcursor, int* __restrict__ start,
                                                 unsigned char* __restrict__ Ps) {
    __shared__ int sc[256];
    int t = threadIdx.x;
    int v = (t < NB1) ? deg[t] : 0;
    sc[t] = v; __syncthreads();
    for (int off = 1; off < 256; off <<= 1) {
        int y = (t >= off) ? sc[t - off] : 0; __syncthreads();
        sc[t] += y; __syncthreads();
    }
    if (t < NB1) {
        int ex = sc[t] - v;
        cbase[t] = ex;
        gcursor[t] = ex;
    }
    if (t == NB1 - 1) cbase[NB1] = sc[t];
    if (t == 0) start[NN] = EE;
    if (t < 64) ((unsigned short*)(Ps + PADOFF))[t] = 0xFF00;  // [F8=0|S8=-448]
}

// chunk -> LDS sort by bucket -> coalesced run writeout. 196 blocks x 1024.
__global__ __launch_bounds__(1024) void k_bin(const int* __restrict__ ei, int* __restrict__ gcursor,
                                              unsigned int* __restrict__ ebuf1) {
    __shared__ int hist[NB1];
    __shared__ int lpre[NB1 + 1];
    __shared__ int gbase[NB1];
    __shared__ int sc[256];
    __shared__ unsigned int staged[CHK];
    int t = threadIdx.x;
    if (t < NB1) hist[t] = 0;
    __syncthreads();
    int e0 = blockIdx.x * CHK;
    unsigned int pk[4]; int rk[4], bk[4];
    #pragma unroll
    for (int i = 0; i < 4; ++i) {
        int e = e0 + t + 1024 * i;
        if (e < EE) {
            int src = ei[e], dst = ei[EE + e];
            bk[i] = dst >> 8;
            pk[i] = ((unsigned)(dst & 255) << 17) | (unsigned)src;
            rk[i] = atomicAdd(&hist[bk[i]], 1);
        } else bk[i] = -1;
    }
    __syncthreads();
    {   // parallel exclusive scan of hist -> lpre
        int hv = (t < 256) ? ((t < NB1) ? hist[t] : 0) : 0;
        if (t < 256) sc[t] = hv;
        __syncthreads();
        for (int off = 1; off < 256; off <<= 1) {
            int y = (t < 256 && t >= off) ? sc[t - off] : 0; __syncthreads();
            if (t < 256) sc[t] += y;
            __syncthreads();
        }
        if (t < NB1) lpre[t] = sc[t] - hv;
        if (t == NB1 - 1) lpre[NB1] = sc[t];
        __syncthreads();
    }
    if (t < NB1 && hist[t]) gbase[t] = atomicAdd(&gcursor[t], hist[t]);
    #pragma unroll
    for (int i = 0; i < 4; ++i)
        if (bk[i] >= 0) staged[lpre[bk[i]] + rk[i]] = pk[i];
    __syncthreads();
    int total = lpre[NB1];
    for (int k = t; k < total; k += 1024) {
        int lo = 0, hi = NB1 - 1;
        while (lo < hi) { int mid = (lo + hi + 1) >> 1; if (lpre[mid] <= k) lo = mid; else hi = mid - 1; }
        ebuf1[gbase[lo] + (k - lpre[lo])] = staged[k];
    }
}

// exact per-node grouping within a bucket; coalesced esrc (byte offsets
// src*128) + per-node start.
__global__ __launch_bounds__(1024) void k_group(const unsigned int* __restrict__ ebuf1,
                                                const int* __restrict__ cbase,
                                                int* __restrict__ esrc, int* __restrict__ start) {
    __shared__ int hist[BSZ];
    __shared__ int lpre[BSZ];
    __shared__ int sc[BSZ];
    __shared__ int staged[GCAP];
    int t = threadIdx.x;
    int b = blockIdx.x;
    if (t < BSZ) hist[t] = 0;
    __syncthreads();
    int e0 = cbase[b], e1 = cbase[b + 1];
    int cnt = e1 - e0;
    if (cnt > GCAP) cnt = GCAP;
    int src[5], rk[5], dl[5]; int m = 0;
    for (int k = t; k < cnt; k += 1024) {
        unsigned int p = ebuf1[e0 + k];
        int d = (int)(p >> 17);
        src[m] = (int)(p & 0x1FFFFu);
        dl[m] = d;
        rk[m] = atomicAdd(&hist[d], 1);
        if (++m == 5) break;
    }
    __syncthreads();
    {   // parallel exclusive scan hist -> lpre
        int hv = (t < BSZ) ? hist[t] : 0;
        if (t < BSZ) sc[t] = hv;
        __syncthreads();
        for (int off = 1; off < BSZ; off <<= 1) {
            int y = (t < BSZ && t >= off) ? sc[t - off] : 0; __syncthreads();
            if (t < BSZ) sc[t] += y;
            __syncthreads();
        }
        if (t < BSZ) lpre[t] = sc[t] - hv;
        __syncthreads();
    }
    for (int i = 0; i < m; ++i)
        staged[lpre[dl[i]] + rk[i]] = src[i];
    __syncthreads();
    for (int k = t; k < cnt; k += 1024)
        esrc[e0 + k] = staged[k] * 128;     // byte offset into Ps
    int node = b * BSZ + t;
    if (t < BSZ && node < NN)
        start[node] = e0 + lpre[t];
}

// P = H @ Wcat (R16). MODE 0: layer1 (x). MODE 1: layer2 fused residual.
// Epilogue: LDS-staged Pd/Ps tiles (reusing w_s), coalesced uint4 dump.
template <int MODE>
__global__ __launch_bounds__(256) void k_proj(const float* __restrict__ x,
                                              const unsigned short* __restrict__ agg,
                                              unsigned short* __restrict__ h1b,
                                              const unsigned short* __restrict__ wt,
                                              const float* __restrict__ bfv, const float* __restrict__ bsv,
                                              unsigned short* __restrict__ Pd, unsigned char* __restrict__ Ps) {
    __shared__ unsigned short w_s[256 * 64];
    __shared__ unsigned short a_s[64 * 64];
    const int t = threadIdx.x;
    {
        const uint4v* src = (const uint4v*)wt;
        uint4v* dp = (uint4v*)w_s;
        #pragma unroll
        for (int i = 0; i < 8; ++i) dp[t + 256 * i] = src[t + 256 * i];
    }
    const int lane = t & 63, wid = t >> 6;
    const int cbase = lane & 15, q = lane >> 4;
    const int tile = blockIdx.x;

    #pragma unroll
    for (int i = 0; i < 2; ++i) {
        int ch = t + 256 * i;
        int r = ch >> 3, c8 = ch & 7;
        int node = tile * 64 + r;
        u16x4 lo = {0, 0, 0, 0}, hi = {0, 0, 0, 0};
        if (node < NN) {
            const float* xp = x + node * 64 + c8 * 8;
            f32x4 v0 = *(const f32x4*)xp;
            f32x4 v1 = *(const f32x4*)(xp + 4);
            if (MODE == 1) {
                const unsigned short* ap = agg + node * 64 + c8 * 8;
                u16x4 a0 = *(const u16x4*)ap;
                u16x4 a1 = *(const u16x4*)(ap + 4);
                #pragma unroll
                for (int j = 0; j < 4; ++j) {
                    v0[j] += LN2F * b2f(a0[j]);
                    v1[j] += LN2F * b2f(a1[j]);
                }
            }
            lo[0] = f2b(v0[0]); lo[1] = f2b(v0[1]); lo[2] = f2b(v0[2]); lo[3] = f2b(v0[3]);
            hi[0] = f2b(v1[0]); hi[1] = f2b(v1[1]); hi[2] = f2b(v1[2]); hi[3] = f2b(v1[3]);
            if (MODE == 1) {
                unsigned short* hp = h1b + node * 64 + c8 * 8;
                *(u16x4*)hp = lo;
                *(u16x4*)(hp + 4) = hi;
            }
        }
        int byte = (r * 128 + c8 * 16) ^ ((r & 7) << 4);
        *(u16x4*)((char*)a_s + byte) = lo;
        *(u16x4*)((char*)a_s + byte + 8) = hi;
    }
    __syncthreads();

    f32x4 acc[4][4];
    #pragma unroll
    for (int m = 0; m < 4; ++m)
        #pragma unroll
        for (int n = 0; n < 4; ++n) acc[m][n] = (f32x4){0.f, 0.f, 0.f, 0.f};

    #pragma unroll
    for (int ks = 0; ks < 2; ++ks) {
        bf16x8 a[4];
        #pragma unroll
        for (int m = 0; m < 4; ++m) {
            int mr = m * 16 + cbase;
            a[m] = *(const bf16x8*)((const char*)a_s + mr * 128 + ((ks * 64 + q * 16) ^ ((mr & 7) << 4)));
        }
        #pragma unroll
        for (int n = 0; n < 4; ++n) {
            int bn = wid * 64 + n * 16 + cbase;
            bf16x8 b = *(const bf16x8*)((const char*)w_s + bn * 128 + ((ks * 64 + q * 16) ^ ((bn & 7) << 4)));
            #pragma unroll
            for (int m = 0; m < 4; ++m)
                acc[m][n] = __builtin_amdgcn_mfma_f32_16x16x32_bf16(a[m], b, acc[m][n], 0, 0, 0);
        }
    }

    __syncthreads();
    unsigned short* pdo = w_s;                              // 64x128 u16 (16KB)
    unsigned char*  pso = (unsigned char*)(w_s + 8192);     // 64x128 u8 (8KB)

    #pragma unroll
    for (int n = 0; n < 4; ++n) {
        int col = wid * 64 + n * 16 + cbase;
        if (col < 128) {
            int oidx = (col < 64) ? 2 * col : 2 * (col - 64) + 1;
            float scale = (col < 64) ? -L2EF : L2EF;
            #pragma unroll
            for (int m = 0; m < 4; ++m) {
                int row = m * 16 + q * 4;
                #pragma unroll
                for (int r = 0; r < 4; ++r)
                    pdo[(row + r) * 128 + oidx] = f2b(acc[m][n][r] * scale);
            }
        } else {
            float bias, scale; int boff;
            if (col < 192) { scale = -L2EF; bias = bfv[col - 128]; boff = 2 * (col - 128); }
            else           { scale =  L2EF; bias = bsv[col - 192]; boff = 2 * (col - 192) + 1; }
            #pragma unroll
            for (int m = 0; m < 4; ++m) {
                int row = m * 16 + q * 4;
                #pragma unroll
                for (int r = 0; r < 4; ++r)
                    pso[(row + r) * 128 + boff] = f2fp8((acc[m][n][r] + bias) * scale);
            }
        }
    }
    __syncthreads();
    {
        uint4v* pdg = (uint4v*)(Pd + tile * 64 * 128);
        const uint4v* pdl = (const uint4v*)pdo;
        #pragma unroll
        for (int i = 0; i < 4; ++i) pdg[t + 256 * i] = pdl[t + 256 * i];
        uint4v* psg = (uint4v*)(Ps + tile * 64 * 128);
        const uint4v* psl = (const uint4v*)pso;
        #pragma unroll
        for (int i = 0; i < 2; ++i) psg[t + 256 * i] = psl[t + 256 * i];
    }
}

// Gather: 8-deep banks, guard-free pads (dummy row -> msg==0), sentinel nend.
__global__ __launch_bounds__(256) void k_glean(const unsigned int* __restrict__ Pd,
                                               const unsigned char* __restrict__ Ps,
                                               const int* __restrict__ esrc, const int* __restrict__ start,
                                               unsigned short* __restrict__ agg) {
    __shared__ int idx_s[4][224];
    __shared__ int end_s[4][32];
    __shared__ unsigned int pd_s[4][1024];
    const int lane = threadIdx.x & 63;
    const int wid = threadIdx.x >> 6;
    const int w = blockIdx.x * 4 + wid;

    int t0 = w * EPW, t1 = t0 + EPW;
    int lo = 0, hi = NN;
    while (lo < hi) { int mid = (lo + hi) >> 1; if (start[mid] < t0) lo = mid + 1; else hi = mid; }
    const int n0 = lo;
    hi = NN;
    while (lo < hi) { int mid = (lo + hi) >> 1; if (start[mid] < t1) lo = mid + 1; else hi = mid; }
    const int n1 = lo;
    const int nn = n1 - n0;
    const int nn16 = (nn < 16) ? nn : 16;

    const int e0 = __builtin_amdgcn_readfirstlane(start[n0]);
    const int cnt = __builtin_amdgcn_readfirstlane(start[n1]) - e0;
    int* idxp = idx_s[wid];
    for (int k = lane; k < cnt + 16; k += 64)
        idxp[k] = (k < cnt) ? esrc[e0 + k] : PADOFF;
    int* endp = end_s[wid];
    if (lane < 32)
        endp[lane] = (lane < nn && lane < 31) ? (start[n0 + 1 + lane] - e0) : 0x7fffffff;
    unsigned int* pdp = pd_s[wid];
    for (int i = 0; i < nn16; ++i)
        pdp[i * 64 + lane] = Pd[(n0 + i) * 64 + lane];

    const char* Psc = (const char*)Ps;
    const int lane2 = lane * 2;

    int n = n0;
    int nend = 0x7fffffff;
    float acc = 0.f, nfd = 0.f, sd = 0.f;
    if (nn > 0) {
        unsigned int pv = pdp[lane];
        nfd = lo16f(pv); sd = hi16f(pv);
        nend = endp[0];
    }

#define FLUSH() do {                                                          \
    agg[n * 64 + lane] = f2b(acc);                                            \
    ++n; acc = 0.f;                                                           \
    int ii_ = n - n0;                                                         \
    unsigned int pv_;                                                         \
    if (ii_ < 16) pv_ = pdp[ii_ * 64 + lane];                                 \
    else pv_ = Pd[((n < NN) ? n : NN - 1) * 64 + lane];                       \
    nfd = lo16f(pv_); sd = hi16f(pv_);                                        \
    nend = (ii_ < 31) ? endp[ii_]                                             \
                      : ((n < n1) ? (__builtin_amdgcn_readfirstlane(start[n + 1]) - e0) \
                                  : 0x7fffffff);                              \
} while (0)

#define LOADB(vv, kb_) do {                                                   \
    int4v j0_ = *(const int4v*)(idxp + (kb_));                                \
    int4v j1_ = *(const int4v*)(idxp + (kb_) + 4);                            \
    vv[0] = *(const unsigned short*)(Psc + j0_[0] + lane2);                   \
    vv[1] = *(const unsigned short*)(Psc + j0_[1] + lane2);                   \
    vv[2] = *(const unsigned short*)(Psc + j0_[2] + lane2);                   \
    vv[3] = *(const unsigned short*)(Psc + j0_[3] + lane2);                   \
    vv[4] = *(const unsigned short*)(Psc + j1_[0] + lane2);                   \
    vv[5] = *(const unsigned short*)(Psc + j1_[1] + lane2);                   \
    vv[6] = *(const unsigned short*)(Psc + j1_[2] + lane2);                   \
    vv[7] = *(const unsigned short*)(Psc + j1_[3] + lane2);                   \
} while (0)

#define COMP(vv, kb_) do {                                                    \
    _Pragma("unroll")                                                         \
    for (int i_ = 0; i_ < 8; ++i_) {                                          \
        int k_ = (kb_) + i_;                                                  \
        while (k_ == nend) FLUSH();                                           \
        acc += msg2(nfd + fp8lo(vv[i_]), sd + fp8hi(vv[i_]));                 \
    }                                                                         \
} while (0)

    if (cnt > 0) {
        unsigned int vA[8], vB[8];
        LOADB(vA, 0);
        int kb = 0;
        while (true) {
            LOADB(vB, kb + 8);
            COMP(vA, kb);
            kb += 8; if (kb >= cnt) break;
            LOADB(vA, kb + 8);
            COMP(vB, kb);
            kb += 8; if (kb >= cnt) break;
        }
    }
    while (n < n1) FLUSH();
#undef FLUSH
#undef LOADB
#undef COMP
}

// readout + fused final (done-counter in scal[2]).
__global__ __launch_bounds__(256) void k_post2(const unsigned short* __restrict__ h1b,
                                               const unsigned short* __restrict__ agg,
                                               const float* __restrict__ surf, const float* __restrict__ Wlin,
                                               const float* __restrict__ blin,
                                               float* __restrict__ scal, float* __restrict__ out) {
    const int lane = threadIdx.x & 63, wid = threadIdx.x >> 6;
    float wl = Wlin[lane];
    float so = 0.f, ss = 0.f;
    for (int n = blockIdx.x * 4 + wid; n < NN; n += gridDim.x * 4) {
        int i = n * 64 + lane;
        float h2 = b2f(h1b[i]) + LN2F * b2f(agg[i]);
        float v = h2 * wl;
        #pragma unroll
        for (int off = 32; off; off >>= 1) v += __shfl_xor(v, off);
        if (lane == 0) { so += v * surf[n]; ss += surf[n]; }
    }
    __shared__ float ps[8];
    if (lane == 0) { ps[wid] = so; ps[4 + wid] = ss; }
    __syncthreads();
    if (threadIdx.x == 0) {
        atomicAdd(scal + 0, ps[0] + ps[1] + ps[2] + ps[3]);
        atomicAdd(scal + 1, ps[4] + ps[5] + ps[6] + ps[7]);
        __threadfence();
        unsigned done = atomicAdd((unsigned int*)(scal + 2), 1u);
        if (done == gridDim.x - 1) {
            float num = atomicAdd(scal + 0, 0.f);
            float den = atomicAdd(scal + 1, 0.f);
            out[0] = (num + (float)NN * blin[0]) / den;
        }
    }
}

extern "C" void kernel_launch(void* const* d_in, const int* in_sizes, int n_in,
                              void* d_out, int out_size, void* d_ws, size_t ws_size,
                              hipStream_t stream) {
    const float* x    = (const float*)d_in[0];
    const int*   ei   = (const int*)d_in[1];
    const float* surf = (const float*)d_in[2];
    const float* Wf1  = (const float*)d_in[3];
    const float* bf1  = (const float*)d_in[4];
    const float* Ws1  = (const float*)d_in[5];
    const float* bs1  = (const float*)d_in[6];
    const float* Wf2  = (const float*)d_in[7];
    const float* bf2  = (const float*)d_in[8];
    const float* Ws2  = (const float*)d_in[9];
    const float* bs2  = (const float*)d_in[10];
    const float* Wlin = (const float*)d_in[11];
    const float* blin = (const float*)d_in[12];

    unsigned char* ws = (unsigned char*)d_ws;
    int* deg      = (int*)(ws);                              // 784 (pad 1024)
    float* scal   = (float*)(ws + 1024);                     // 64 (scal[2]=done)
    int* cbase    = (int*)(ws + 1088);                       // 788 (pad to 2048)
    int* gcursor  = (int*)(ws + 2048);                       // 784
    int* start    = (int*)(ws + 4096);                       // 200,004
    unsigned int* ebuf1 = (unsigned int*)(ws + 204800);      // 3,200,000
    int* esrc     = (int*)(ws + 3404800);                    // 3,200,000
    unsigned short* h1b = (unsigned short*)(ws + 6604800);   // 6,406,144
    unsigned short* Pd  = (unsigned short*)(ws + 13010944);  // 12,812,288
    unsigned char*  Ps  = (unsigned char*)(ws + 25823232);   // 6,406,144 + 128 (dummy row)
    unsigned short* agg = (unsigned short*)(ws + 32229504);  // 6,406,144
    unsigned short* wt  = (unsigned short*)(ws + 38635648);  // 65,536

    hipMemsetAsync(d_ws, 0, 1088, stream);  // deg + scal (incl done-counter)

    k_hist<<<98, 1024, 0, stream>>>(ei, deg, Wf1, Ws1, Wf2, Ws2, wt);
    k_scan196<<<1, 256, 0, stream>>>(deg, cbase, gcursor, start, Ps);
    k_bin<<<196, 1024, 0, stream>>>(ei, gcursor, ebuf1);
    k_group<<<196, 1024, 0, stream>>>(ebuf1, cbase, esrc, start);

    k_proj<0><<<NTILE, 256, 0, stream>>>(x, agg, h1b, wt, bf1, bs1, Pd, Ps);
    k_glean<<<2048, 256, 0, stream>>>((const unsigned int*)Pd, Ps, esrc, start, agg);
    k_proj<1><<<NTILE, 256, 0, stream>>>(x, agg, h1b, wt + 16384, bf2, bs2, Pd, Ps);
    k_glean<<<2048, 256, 0, stream>>>((const unsigned int*)Pd, Ps, esrc, start, agg);
    k_post2<<<512, 256, 0, stream>>>(h1b, agg, surf, Wlin, blin, scal, (float*)d_out);
}